// Round 14
// baseline (112.919 us; speedup 1.0000x reference)
//
#include <hip/hip_runtime.h>
#include <cstdint>
#include <cstddef>

// Problem constants
#define BB   2
#define SS   2048
#define DD   512
#define HH   8
#define HDIM 64
#define XN   ((size_t)BB * SS * DD)   // 2,097,152
#define WN   ((size_t)DD * DD)        //   262,144

typedef __attribute__((ext_vector_type(8)))  short          s16x8;
typedef __attribute__((ext_vector_type(8)))  unsigned short u16x8;
typedef __attribute__((ext_vector_type(16))) float          f32x16;

static __device__ __forceinline__ unsigned short f2bf(float f) {
  union { float f; unsigned u; } x; x.f = f;
  unsigned r = x.u + 0x7fffu + ((x.u >> 16) & 1u);  // RNE
  return (unsigned short)(r >> 16);
}
// truncating bf16 pack: result = bf(hi)<<16 | bf(lo), ONE v_perm_b32
static __device__ __forceinline__ unsigned packtrunc(float lo, float hi) {
  return __builtin_amdgcn_perm(__float_as_uint(hi), __float_as_uint(lo), 0x07060302u);
}

// sigmoid scale folded into Q: -1/sqrt(64) * log2(e)
#define QSCALE (-0.18033688011111543f)

// ---------------- fp32 -> bf16 conversion of x, wq, wk, wv --------------------------
// grid (2048, 4): y=0 -> x (2048 blocks); y=1..3 -> wq/wk/wv (first 256 blocks each).
__global__ __launch_bounds__(256) void cvt_kernel(
    const float* __restrict__ x,
    const float* __restrict__ wq, const float* __restrict__ wk, const float* __restrict__ wv,
    unsigned short* __restrict__ xb, unsigned short* __restrict__ wb3) {
  const int y = blockIdx.y;
  const float* src; unsigned short* dst;
  if (y == 0) { src = x; dst = xb; }
  else {
    if (blockIdx.x >= 256) return;
    src = (y == 1) ? wq : (y == 2) ? wk : wv;
    dst = wb3 + (size_t)(y - 1) * WN;
  }
  int i = (blockIdx.x * 256 + threadIdx.x) * 4;
  float4 f = *(const float4*)(src + i);
  ushort4 o;
  o.x = f2bf(f.x); o.y = f2bf(f.y); o.z = f2bf(f.z); o.w = f2bf(f.w);
  *(ushort4*)(dst + i) = o;
}

// ---------------- QKV projection (bf16 inputs) --------------------------------------
// grid (M/128=32, N/64=8, 3) = 768 blocks = 3/CU. 256 threads = 4 waves; wave owns a
// 32-row strip x 64 cols (2 accs). BK=32, 16 iters, LDS dbuf + reg prefetch.
// Outputs: z=0 Q [B][H][S][HD] scaled; z=1 K MFMA A-frag order; z=2 V B-frag order
// with PI key permutation baked in.
__global__ __launch_bounds__(256) void proj_kernel(
    const unsigned short* __restrict__ xb, const unsigned short* __restrict__ wb3,
    const float* __restrict__ bq, const float* __restrict__ bk, const float* __restrict__ bv,
    unsigned short* __restrict__ qo, unsigned short* __restrict__ ko,
    unsigned short* __restrict__ vt) {
  __shared__ unsigned short As[2][128 * 40];
  __shared__ unsigned short Bs[2][64 * 40];

  const int z = blockIdx.z;
  const unsigned short* w = wb3 + (size_t)z * WN;
  const float* bias = (z == 0) ? bq : (z == 1) ? bk : bv;

  const int t = threadIdx.x;
  const int lane = t & 63, wave = t >> 6;
  const int ln = lane & 31, hi = lane >> 5;
  const int m0 = blockIdx.x * 128, n0 = blockIdx.y * 64;

  u16x8 ar[2], br;
#pragma unroll
  for (int i = 0; i < 2; i++) {
    int c = t + i * 256;
    ar[i] = *(const u16x8*)&xb[(size_t)(m0 + (c >> 2)) * DD + (c & 3) * 8];
  }
  br = *(const u16x8*)&w[(size_t)(n0 + (t >> 2)) * DD + (t & 3) * 8];
#pragma unroll
  for (int i = 0; i < 2; i++) {
    int c = t + i * 256;
    *(u16x8*)&As[0][(c >> 2) * 40 + (c & 3) * 8] = ar[i];
  }
  *(u16x8*)&Bs[0][(t >> 2) * 40 + (t & 3) * 8] = br;
  __syncthreads();

  f32x16 acc0 = {}, acc1 = {};

#pragma unroll 2
  for (int kt = 0; kt < 16; kt++) {
    const int cur = kt & 1, nxt = cur ^ 1;
    if (kt < 15) {
      int k0 = (kt + 1) * 32;
#pragma unroll
      for (int i = 0; i < 2; i++) {
        int c = t + i * 256;
        ar[i] = *(const u16x8*)&xb[(size_t)(m0 + (c >> 2)) * DD + k0 + (c & 3) * 8];
      }
      br = *(const u16x8*)&w[(size_t)(n0 + (t >> 2)) * DD + k0 + (t & 3) * 8];
    }
#pragma unroll
    for (int cc = 0; cc < 2; cc++) {
      s16x8 af = *(const s16x8*)&As[cur][(wave * 32 + ln) * 40 + cc * 16 + hi * 8];
      s16x8 b0 = *(const s16x8*)&Bs[cur][(ln) * 40 + cc * 16 + hi * 8];
      s16x8 b1 = *(const s16x8*)&Bs[cur][(32 + ln) * 40 + cc * 16 + hi * 8];
      acc0 = __builtin_amdgcn_mfma_f32_32x32x16_bf16(af, b0, acc0, 0, 0, 0);
      acc1 = __builtin_amdgcn_mfma_f32_32x32x16_bf16(af, b1, acc1, 0, 0, 0);
    }
    if (kt < 15) {
#pragma unroll
      for (int i = 0; i < 2; i++) {
        int c = t + i * 256;
        *(u16x8*)&As[nxt][(c >> 2) * 40 + (c & 3) * 8] = ar[i];
      }
      *(u16x8*)&Bs[nxt][(t >> 2) * 40 + (t & 3) * 8] = br;
    }
    __syncthreads();
  }

  const int h = blockIdx.y;
  const int bidx = m0 >> 11;
  const int sbase = (m0 & 2047) + wave * 32;
  const size_t bhb = (size_t)(bidx * HH + h) * SS * HDIM;
  const int kts = sbase >> 5;

#pragma unroll
  for (int nh = 0; nh < 2; nh++) {
    f32x16 acc = nh ? acc1 : acc0;
    const int hd = nh * 32 + ln;
    const float bval = bias[n0 + hd];

    if (z == 0) {
#pragma unroll
      for (int r = 0; r < 16; r++) {
        int s = sbase + (r & 3) + 8 * (r >> 2) + 4 * hi;
        qo[bhb + (size_t)s * HDIM + hd] = f2bf((acc[r] + bval) * QSCALE);
      }
    } else if (z == 1) {
      const int c = hd >> 4, hk = (hd >> 3) & 1, j = hd & 7;
      unsigned short* kd = ko + bhb + ((size_t)kts * 4 + c) * 512 + j;
#pragma unroll
      for (int r = 0; r < 16; r++) {
        int off = (r & 3) + 8 * (r >> 2) + 4 * hi;
        kd[(hk * 32 + off) * 8] = f2bf(acc[r] + bval);
      }
    } else {
      unsigned short* vd = vt + bhb + ((size_t)kts * 4 + nh * 2) * 512 + hi * 256 + ln * 8;
#pragma unroll
      for (int g = 0; g < 4; g++) {
        unsigned short* vg = vd + (g >> 1) * 512 + (g & 1) * 4;
#pragma unroll
        for (int j = 0; j < 4; j += 2) {
          unsigned pk = (unsigned)f2bf(acc[g * 4 + j] + bval) |
                        ((unsigned)f2bf(acc[g * 4 + j + 1] + bval) << 16);
          *(unsigned*)&vg[j] = pk;
        }
      }
    }
  }
}

// ---------------- fused sigmoid attention: 64q/wave + dbuf frags + unroll 2 ---------
// grid (S/128=16, B*H=16) = 256 blocks x 512 thr = 8 waves = (qp,kh) 2x4: each wave
// 64 queries x key quarter (16 tiles of 32). K/V frag-direct contiguous 1KB loads,
// DOUBLE-buffered (+32 VGPR, ~195 total, still 2 waves/SIMD, <256 cap = no spill) so
// iteration i+1's QK/loads are register-independent of iteration i's sigmoid/PV —
// unroll 2 lets the compiler interleave across tiles and fill the ~500-cyc serial
// chain (R13 rotation created false deps and blocked this). pi-permuted V: P
// A-fragment = lane's own sigmoid pairs. Zero loop barriers.
__global__ __launch_bounds__(512, 2) void attn_kernel(
    const unsigned short* __restrict__ qb,
    const unsigned short* __restrict__ kfb,
    const unsigned short* __restrict__ vfb,
    float* __restrict__ out) {
  __shared__ __align__(16) float red[2 * 8192];  // 64 KB, 2 slots of 128q x 64d

  const int t = threadIdx.x;
  const int lane = t & 63, wave = t >> 6;   // wave 0..7
  const int ln = lane & 31, hi = lane >> 5;
  const int qp = wave & 1, kh = wave >> 1;  // qp: 64-q half, kh: key quarter
  // XCD swizzle: blocks of one bh at ids ≡ mod 16 -> same XCD
  const int fid = blockIdx.y * 16 + blockIdx.x;
  const int bh = fid & 15, qx = fid >> 4;
  const int b = bh >> 3, h = bh & 7;
  const unsigned short* qp_ = qb + (size_t)bh * SS * HDIM;
  const unsigned short* kfp = kfb + (size_t)bh * SS * HDIM;
  const unsigned short* vfp = vfb + (size_t)bh * SS * HDIM;
  const int q0 = qx * 128 + qp * 64;

  // TWO Q fragment sets (B-operand: n=q on lane, k=d)
  s16x8 qf[2][4];
#pragma unroll
  for (int qs = 0; qs < 2; qs++)
#pragma unroll
    for (int c = 0; c < 4; c++)
      qf[qs][c] = *(const s16x8*)&qp_[(size_t)(q0 + qs * 32 + ln) * HDIM + c * 16 + hi * 8];

  f32x16 o00 = {}, o01 = {}, o10 = {}, o11 = {};

  // double-buffered fragments
  s16x8 kf[2][4], vf[2][4];
  int foff = kh * 16 * 2048 + lane * 8;
#pragma unroll
  for (int c = 0; c < 4; c++) {
    kf[0][c] = *(const s16x8*)&kfp[foff + c * 512];
    vf[0][c] = *(const s16x8*)&vfp[foff + c * 512];
  }
  foff += 2048;

#pragma unroll 2
  for (int i = 0; i < 16; i++) {
    const int cur = i & 1, nxt = cur ^ 1;
    // prefetch next tile into the other buffer — independent of this tile's compute
    if (i < 15) {
#pragma unroll
      for (int c = 0; c < 4; c++) {
        kf[nxt][c] = *(const s16x8*)&kfp[foff + c * 512];
        vf[nxt][c] = *(const s16x8*)&vfp[foff + c * 512];
      }
      foff += 2048;
    }

    // QK^T for both q-sets (independent chains — ILP)
    f32x16 st0 = {}, st1 = {};
#pragma unroll
    for (int c = 0; c < 4; c++) {
      st0 = __builtin_amdgcn_mfma_f32_32x32x16_bf16(kf[cur][c], qf[0][c], st0, 0, 0, 0);
      st1 = __builtin_amdgcn_mfma_f32_32x32x16_bf16(kf[cur][c], qf[1][c], st1, 0, 0, 0);
    }

    // sigmoid both sets; pi layout -> pg[qs][4c..4c+3] is the PV A-operand verbatim
    unsigned pg[2][8];
#pragma unroll
    for (int qs = 0; qs < 2; qs++) {
      f32x16 st = qs ? st1 : st0;
#pragma unroll
      for (int g = 0; g < 4; g++) {
        float p0 = __builtin_amdgcn_rcpf(1.0f + __builtin_amdgcn_exp2f(st[4 * g + 0]));
        float p1 = __builtin_amdgcn_rcpf(1.0f + __builtin_amdgcn_exp2f(st[4 * g + 1]));
        float p2 = __builtin_amdgcn_rcpf(1.0f + __builtin_amdgcn_exp2f(st[4 * g + 2]));
        float p3 = __builtin_amdgcn_rcpf(1.0f + __builtin_amdgcn_exp2f(st[4 * g + 3]));
        pg[qs][2 * g]     = packtrunc(p0, p1);
        pg[qs][2 * g + 1] = packtrunc(p2, p3);
      }
    }

    // PV: 8 MFMAs reusing the same vf for both q-sets
#pragma unroll
    for (int c = 0; c < 2; c++) {
#pragma unroll
      for (int qs = 0; qs < 2; qs++) {
        union { unsigned u[4]; s16x8 v; } pu;
        pu.u[0] = pg[qs][4 * c + 0];
        pu.u[1] = pg[qs][4 * c + 1];
        pu.u[2] = pg[qs][4 * c + 2];
        pu.u[3] = pg[qs][4 * c + 3];
        if (qs == 0) {
          o00 = __builtin_amdgcn_mfma_f32_32x32x16_bf16(pu.v, vf[cur][c], o00, 0, 0, 0);
          o01 = __builtin_amdgcn_mfma_f32_32x32x16_bf16(pu.v, vf[cur][2 + c], o01, 0, 0, 0);
        } else {
          o10 = __builtin_amdgcn_mfma_f32_32x32x16_bf16(pu.v, vf[cur][c], o10, 0, 0, 0);
          o11 = __builtin_amdgcn_mfma_f32_32x32x16_bf16(pu.v, vf[cur][2 + c], o11, 0, 0, 0);
        }
      }
    }
  }

  // staged 4-way kh reduction: kh{2,3} -> slots, kh{0,1} add, then pairwise sum.
  if (kh >= 2) {
    float* slot = red + (kh - 2) * 8192;
#pragma unroll
    for (int qs = 0; qs < 2; qs++)
#pragma unroll
      for (int dh = 0; dh < 2; dh++) {
        f32x16 ov = qs ? (dh ? o11 : o10) : (dh ? o01 : o00);
#pragma unroll
        for (int r = 0; r < 16; r++) {
          int ql = qp * 64 + qs * 32 + (r & 3) + 8 * (r >> 2) + 4 * hi;
          slot[ql * 64 + dh * 32 + ln] = ov[r];
        }
      }
  }
  __syncthreads();
  if (kh < 2) {
    float* slot = red + kh * 8192;
#pragma unroll
    for (int qs = 0; qs < 2; qs++)
#pragma unroll
      for (int dh = 0; dh < 2; dh++) {
        f32x16 ov = qs ? (dh ? o11 : o10) : (dh ? o01 : o00);
#pragma unroll
        for (int r = 0; r < 16; r++) {
          int ql = qp * 64 + qs * 32 + (r & 3) + 8 * (r >> 2) + 4 * hi;
          slot[ql * 64 + dh * 32 + ln] += ov[r];
        }
      }
  }
  __syncthreads();
  const float4* r0 = (const float4*)red;
  const float4* r1 = (const float4*)(red + 8192);
  const int qblk = qx * 128;
#pragma unroll
  for (int j = 0; j < 4; j++) {
    int g = t + j * 512;   // 2048 float4s total (128q x 64d)
    float4 s0 = r0[g], s1 = r1[g];
    float4 s;
    s.x = s0.x + s1.x; s.y = s0.y + s1.y; s.z = s0.z + s1.z; s.w = s0.w + s1.w;
    int q = g >> 4, dbase = (g & 15) * 4;
    *(float4*)&out[((size_t)(b * SS + qblk + q)) * DD + h * HDIM + dbase] = s;
  }
}

extern "C" void kernel_launch(void* const* d_in, const int* in_sizes, int n_in,
                              void* d_out, int out_size, void* d_ws, size_t ws_size,
                              hipStream_t stream) {
  const float* x  = (const float*)d_in[0];
  const float* wq = (const float*)d_in[1];
  const float* bq = (const float*)d_in[2];
  const float* wk = (const float*)d_in[3];
  const float* bk = (const float*)d_in[4];
  const float* wv = (const float*)d_in[5];
  const float* bv = (const float*)d_in[6];
  float* out = (float*)d_out;

  unsigned short* xb = (unsigned short*)d_ws;
  unsigned short* wb = xb + XN;
  unsigned short* qo = wb + 3 * WN;
  unsigned short* ko = qo + XN;
  unsigned short* vt = ko + XN;   // ~18.5 MB total ws use

  cvt_kernel<<<dim3(2048, 4), 256, 0, stream>>>(x, wq, wk, wv, xb, wb);
  proj_kernel<<<dim3(32, 8, 3), 256, 0, stream>>>(xb, wb, bq, bk, bv, qo, ko, vt);
  attn_kernel<<<dim3(SS / 128, BB * HH), 512, 0, stream>>>(qo, ko, vt, out);
}